// Round 2
// baseline (62006.360 us; speedup 1.0000x reference)
//
#include <hip/hip_runtime.h>
#include <math.h>

// LSTM: T=2048, B=32, IN=512, H=512, gates 4H=2048.
// Persistent-kernel design:
//   256 blocks x 256 threads. Block g owns h-indices {2g, 2g+1} -> 8 gate
//   columns (4 gates x 2 h-idx) for all 32 batch rows. Weights for those
//   8 columns (W_ih row + W_hh row, K=1024 total) live in LDS for the whole
//   kernel. Cell state c for the block's 64 (b,h) pairs lives in LDS.
//   h(t) is exchanged through d_out (outputs[t] IS h(t)).
//   One grid barrier per timestep (two-level monotonic counter in d_ws).

#define T_STEPS 2048
#define B_SZ    32
#define IN_SZ   512
#define H_SZ    512
#define NBLK    256
#define NTHR    256
#define COLS_PER_BLK 8
#define HI_PER_BLK   2
#define WPAD    1036   // LDS row stride in floats; 1036%32=12 -> 8 rows on distinct banks
#define BAR_GROUPS 16
#define BAR_GSZ    16

__device__ __forceinline__ float sigmoidf_(float x) {
    return 1.0f / (1.0f + __expf(-x));
}
__device__ __forceinline__ float tanhf_(float x) {
    float e = __expf(-2.0f * fabsf(x));
    float t = (1.0f - e) / (1.0f + e);
    return copysignf(t, x);
}

// Two-level grid barrier. bar[0] = global count, bar[1..16] = per-group counts.
// Monotone counters (no reset): after step t, group count == (t+1)*BAR_GSZ,
// global count == (t+1)*BAR_GROUPS.
__device__ __forceinline__ void grid_barrier(int* bar, int t) {
    __syncthreads();   // drains vmcnt for all waves -> prior global stores complete
    if (threadIdx.x == 0) {
        const int grp = (int)blockIdx.x >> 4;
        __builtin_amdgcn_fence(__ATOMIC_RELEASE, "agent");
        int old = __hip_atomic_fetch_add(&bar[1 + grp], 1, __ATOMIC_ACQ_REL,
                                         __HIP_MEMORY_SCOPE_AGENT);
        if (old == (t + 1) * BAR_GSZ - 1) {
            // last arriver of this group for this step
            __hip_atomic_fetch_add(&bar[0], 1, __ATOMIC_ACQ_REL,
                                   __HIP_MEMORY_SCOPE_AGENT);
        }
        while (__hip_atomic_load(&bar[0], __ATOMIC_RELAXED,
                                 __HIP_MEMORY_SCOPE_AGENT) < (t + 1) * BAR_GROUPS) {
            __builtin_amdgcn_s_sleep(4);
        }
        __builtin_amdgcn_fence(__ATOMIC_ACQUIRE, "agent");
    }
    __syncthreads();
}

__global__ void __launch_bounds__(64) lstm_init_kernel(int* bar) {
    if (threadIdx.x < 32) bar[threadIdx.x] = 0;
}

__global__ void __launch_bounds__(NTHR) lstm_persistent(
    const float* __restrict__ seq,   // [T,B,IN]
    const float* __restrict__ h0,    // [B,H]
    const float* __restrict__ c0,    // [B,H]
    const float* __restrict__ W_ih,  // [4H, IN]
    const float* __restrict__ W_hh,  // [4H, H]
    const float* __restrict__ b_ih,  // [4H]
    const float* __restrict__ b_hh,  // [4H]
    float* __restrict__ out,         // [T,B,H] ++ [B,H] ++ [B,H]
    int* bar)
{
    __shared__ float lds_w[COLS_PER_BLK * WPAD];          // [c][k], k: 0..511 W_ih, 512..1023 W_hh
    __shared__ float lds_bias[COLS_PER_BLK];
    __shared__ float lds_g[NTHR];                          // gate values this step
    __shared__ float lds_c[B_SZ * HI_PER_BLK];             // cell state [b*2 + hi]

    const int tid  = (int)threadIdx.x;
    const int blk  = (int)blockIdx.x;
    const int b    = tid >> 3;        // 0..31 batch row
    const int c    = tid & 7;         // 0..7 local column: c = gate*2 + hi
    // local column -> global weight row j = gate*H + (blk*2 + hi)

    // ---- load this block's 8 weight rows into LDS (once) ----
    for (int idx = tid; idx < COLS_PER_BLK * IN_SZ; idx += NTHR) {
        int cc = idx >> 9;            // 0..7
        int k  = idx & 511;
        int g2 = cc >> 1, h2 = cc & 1;
        int j  = g2 * H_SZ + blk * HI_PER_BLK + h2;
        lds_w[cc * WPAD + k]       = W_ih[(size_t)j * IN_SZ + k];
        lds_w[cc * WPAD + 512 + k] = W_hh[(size_t)j * H_SZ + k];
    }
    if (tid < COLS_PER_BLK) {
        int g2 = tid >> 1, h2 = tid & 1;
        int j  = g2 * H_SZ + blk * HI_PER_BLK + h2;
        lds_bias[tid] = b_ih[j] + b_hh[j];
    }
    if (tid < B_SZ * HI_PER_BLK) {
        int bb = tid >> 1, hh = tid & 1;
        lds_c[tid] = c0[(size_t)bb * H_SZ + blk * HI_PER_BLK + hh];
    }
    __syncthreads();

    const float bias = lds_bias[c];
    const float4* wrow_x = reinterpret_cast<const float4*>(&lds_w[c * WPAD]);
    const float4* wrow_h = reinterpret_cast<const float4*>(&lds_w[c * WPAD + IN_SZ]);

    for (int t = 0; t < T_STEPS; ++t) {
        // ---- gate[b][c] = seq[t,b,:] . W_ih[j,:] + h[b,:] . W_hh[j,:] + bias ----
        const float4* x4 = reinterpret_cast<const float4*>(
            seq + ((size_t)t * B_SZ + b) * IN_SZ);
        const float* hbase = (t == 0) ? h0 : (out + (size_t)(t - 1) * B_SZ * H_SZ);
        const float4* h4 = reinterpret_cast<const float4*>(hbase + (size_t)b * H_SZ);

        float4 acc = make_float4(0.f, 0.f, 0.f, 0.f);
        #pragma unroll 8
        for (int k4 = 0; k4 < IN_SZ / 4; ++k4) {
            float4 a = x4[k4];
            float4 w = wrow_x[k4];
            acc.x += a.x * w.x; acc.y += a.y * w.y;
            acc.z += a.z * w.z; acc.w += a.w * w.w;
        }
        #pragma unroll 8
        for (int k4 = 0; k4 < H_SZ / 4; ++k4) {
            float4 a = h4[k4];
            float4 w = wrow_h[k4];
            acc.x += a.x * w.x; acc.y += a.y * w.y;
            acc.z += a.z * w.z; acc.w += a.w * w.w;
        }
        lds_g[tid] = acc.x + acc.y + acc.z + acc.w + bias;
        __syncthreads();

        // ---- gate nonlinearities + state update (64 threads: one per (b,hi)) ----
        if (tid < B_SZ * HI_PER_BLK) {
            int bb = tid >> 1, hh = tid & 1;
            int base = bb * 8 + hh;           // c = gate*2 + hh
            float iv = sigmoidf_(lds_g[base + 0]);
            float fv = sigmoidf_(lds_g[base + 2]);
            float gv = tanhf_  (lds_g[base + 4]);
            float ov = sigmoidf_(lds_g[base + 6]);
            float cn = fv * lds_c[tid] + iv * gv;
            lds_c[tid] = cn;
            float hn = ov * tanhf_(cn);
            size_t hcol = (size_t)(blk * HI_PER_BLK + hh);
            out[((size_t)t * B_SZ + bb) * H_SZ + hcol] = hn;
            if (t == T_STEPS - 1) {
                // h_f, c_f appended after outputs
                out[((size_t)T_STEPS * B_SZ + bb) * H_SZ + hcol] = hn;
                out[((size_t)T_STEPS * B_SZ + B_SZ + bb) * H_SZ + hcol] = cn;
            }
        }

        if (t != T_STEPS - 1) grid_barrier(bar, t);
    }
}

extern "C" void kernel_launch(void* const* d_in, const int* in_sizes, int n_in,
                              void* d_out, int out_size, void* d_ws, size_t ws_size,
                              hipStream_t stream) {
    const float* seq  = (const float*)d_in[0];
    const float* h0   = (const float*)d_in[1];
    const float* c0   = (const float*)d_in[2];
    const float* W_ih = (const float*)d_in[3];
    const float* W_hh = (const float*)d_in[4];
    const float* b_ih = (const float*)d_in[5];
    const float* b_hh = (const float*)d_in[6];
    float* out = (float*)d_out;
    int* bar = (int*)d_ws;

    lstm_init_kernel<<<1, 64, 0, stream>>>(bar);
    lstm_persistent<<<NBLK, NTHR, 0, stream>>>(seq, h0, c0, W_ih, W_hh,
                                               b_ih, b_hh, out, bar);
}

// Round 3
// 17493.828 us; speedup vs baseline: 3.5445x; 3.5445x over previous
//
#include <hip/hip_runtime.h>
#include <math.h>

// LSTM T=2048, B=32, IN=512, H=512. Persistent kernel, 64 blocks x 256 thr.
// Block owns 8 h-indices -> 32 gate cols (4 gates x 8). Weights bf16 in LDS
// packed in MFMA B-frag order. A (x||h) loaded global->regs as bf16 frags.
// One MFMA tile C[32x32] per block per step, K=1024 split over 4 waves,
// reduced via LDS. h exchanged through d_out with write-through atomic
// stores + flag-array grid barrier (block0 wave0 aggregates).

#define T_STEPS 2048
#define B_SZ    32
#define IN_SZ   512
#define H_SZ    512
#define NBLK    64
#define NTHR    256
#define HPB     8     // h-indices per block
#define NCOL    32    // gate columns per block

typedef __attribute__((ext_vector_type(8)))  short short8;
typedef __attribute__((ext_vector_type(16))) float f32x16;

__device__ __forceinline__ unsigned short f2bf(float f) {
    unsigned int u = __builtin_bit_cast(unsigned int, f);
    u += 0x7fffu + ((u >> 16) & 1u);        // round-to-nearest-even
    return (unsigned short)(u >> 16);
}
__device__ __forceinline__ float sigmoidf_(float x) { return 1.f / (1.f + __expf(-x)); }
__device__ __forceinline__ float tanhf_(float x) {
    float e = __expf(-2.f * fabsf(x));
    float t = (1.f - e) / (1.f + e);
    return copysignf(t, x);
}
__device__ __forceinline__ short8 load_cvt8(const float* p) {
    float4 a = *reinterpret_cast<const float4*>(p);
    float4 b = *reinterpret_cast<const float4*>(p + 4);
    short8 r;
    r[0] = (short)f2bf(a.x); r[1] = (short)f2bf(a.y);
    r[2] = (short)f2bf(a.z); r[3] = (short)f2bf(a.w);
    r[4] = (short)f2bf(b.x); r[5] = (short)f2bf(b.y);
    r[6] = (short)f2bf(b.z); r[7] = (short)f2bf(b.w);
    return r;
}

__global__ void __launch_bounds__(NTHR) lstm_init_kernel(int* ws) {
    for (int i = threadIdx.x; i < 1040; i += NTHR) ws[i] = 0;
}

__global__ void __launch_bounds__(NTHR) lstm_persistent(
    const float* __restrict__ seq,   // [T,B,IN]
    const float* __restrict__ h0,    // [B,H]
    const float* __restrict__ c0,    // [B,H]
    const float* __restrict__ W_ih,  // [4H, IN]
    const float* __restrict__ W_hh,  // [4H, H]
    const float* __restrict__ b_ih,  // [4H]
    const float* __restrict__ b_hh,  // [4H]
    float* __restrict__ out,         // [T,B,H] ++ h_f[B,H] ++ c_f[B,H]
    int* ws)                         // [0]=go, [16+16*b]=flag[b]
{
    __shared__ short Bl[4096 * 8];   // 64 KB: slot ch=(ktg*64+kg*32+col) -> 8 bf16
    __shared__ float Gp[4 * 1024];   // 16 KB: per-wave partial C[32x32]
    __shared__ float biasl[NCOL];

    const int tid = (int)threadIdx.x;
    const int blk = (int)blockIdx.x;
    const int l   = tid & 63;        // lane
    const int wv  = tid >> 6;        // wave 0..3
    const int row = l & 31;          // A row (batch) this lane supplies
    const int kg8 = (l >> 5) * 8;    // k-subgroup offset within 16-wide K tile
    const int m   = tid >> 3;        // epilogue: batch row 0..31
    const int hi  = tid & 7;         // epilogue: local h index 0..7
    const int colh = blk * HPB + hi; // global h column

    // ---- pack weights into B-fragment order (once) ----
    for (int ch = tid; ch < 4096; ch += NTHR) {
        int ktg = ch >> 6, sub = ch & 63, kg = sub >> 5, col = sub & 31;
        int j  = (col >> 3) * H_SZ + blk * HPB + (col & 7);  // gate*512 + h-idx
        int kb = ktg * 16 + kg * 8;
        const float* src = (kb < IN_SZ) ? (W_ih + (size_t)j * IN_SZ + kb)
                                        : (W_hh + (size_t)j * H_SZ + (kb - IN_SZ));
        *reinterpret_cast<short8*>(&Bl[ch * 8]) = load_cvt8(src);
    }
    if (tid < NCOL) {
        int j = (tid >> 3) * H_SZ + blk * HPB + (tid & 7);
        biasl[tid] = b_ih[j] + b_hh[j];
    }

    float cstate = c0[(size_t)m * H_SZ + colh];

    // ---- prologue: frags for t=0 ----
    short8 xfrag[8], hfrag[8];
    #pragma unroll
    for (int i = 0; i < 8; ++i) {
        int koff = (wv * 8 + i) * 16 + kg8;
        xfrag[i] = load_cvt8(seq + (size_t)row * IN_SZ + koff);
        hfrag[i] = load_cvt8(h0 + (size_t)row * H_SZ + koff);
    }
    __syncthreads();   // B pack visible

    const short8* Bv = reinterpret_cast<const short8*>(Bl);

    for (int t = 0; t < T_STEPS; ++t) {
        // ---- MFMA: partial C[32x32] over this wave's K quarter ----
        f32x16 acc = {0.f,0.f,0.f,0.f,0.f,0.f,0.f,0.f,
                      0.f,0.f,0.f,0.f,0.f,0.f,0.f,0.f};
        #pragma unroll
        for (int i = 0; i < 8; ++i)
            acc = __builtin_amdgcn_mfma_f32_32x32x16_bf16(
                xfrag[i], Bv[(wv * 8 + i) * 64 + l], acc, 0, 0, 0);
        #pragma unroll
        for (int i = 0; i < 8; ++i)
            acc = __builtin_amdgcn_mfma_f32_32x32x16_bf16(
                hfrag[i], Bv[(32 + wv * 8 + i) * 64 + l], acc, 0, 0, 0);

        #pragma unroll
        for (int r = 0; r < 16; ++r) {
            int rrow = (r & 3) + 8 * (r >> 2) + 4 * (l >> 5);
            Gp[wv * 1024 + rrow * 32 + (l & 31)] = acc[r];
        }
        __syncthreads();

        // ---- epilogue: reduce 4 partials, gates, state update ----
        float pg[4];
        #pragma unroll
        for (int g = 0; g < 4; ++g) {
            float s = biasl[g * 8 + hi];
            #pragma unroll
            for (int w4 = 0; w4 < 4; ++w4)
                s += Gp[w4 * 1024 + m * 32 + g * 8 + hi];
            pg[g] = s;
        }
        float iv = sigmoidf_(pg[0]);
        float fv = sigmoidf_(pg[1]);
        float gv = tanhf_(pg[2]);
        float ov = sigmoidf_(pg[3]);
        cstate = fv * cstate + iv * gv;
        float hn = ov * tanhf_(cstate);
        // write-through (agent-coherent) store: out[t] IS h(t)
        __hip_atomic_store(out + ((size_t)t * B_SZ + m) * H_SZ + colh, hn,
                           __ATOMIC_RELAXED, __HIP_MEMORY_SCOPE_AGENT);
        if (t == T_STEPS - 1) {
            size_t base = (size_t)T_STEPS * B_SZ * H_SZ;
            out[base + (size_t)m * H_SZ + colh] = hn;                    // h_f
            out[base + (size_t)B_SZ * H_SZ + (size_t)m * H_SZ + colh] = cstate; // c_f
            break;
        }
        __syncthreads();   // drains vmcnt per wave: h-stores + Gp reads complete

        // ---- grid barrier (flag array + aggregator) ----
        if (tid == 0) {
            __builtin_amdgcn_fence(__ATOMIC_RELEASE, "agent");
            __hip_atomic_store(ws + 16 + blk * 16, t + 1,
                               __ATOMIC_RELAXED, __HIP_MEMORY_SCOPE_AGENT);
        }
        if (blk == 0 && wv == 0) {
            int v;
            do {
                v = __hip_atomic_load(ws + 16 + l * 16, __ATOMIC_RELAXED,
                                      __HIP_MEMORY_SCOPE_AGENT);
            } while (!__all(v >= t + 1));
            if (tid == 0)
                __hip_atomic_store(ws, t + 1, __ATOMIC_RELAXED,
                                   __HIP_MEMORY_SCOPE_AGENT);
        }

        // ---- prefetch x(t+1) into regs (overlaps barrier latency) ----
        #pragma unroll
        for (int i = 0; i < 8; ++i) {
            int koff = (wv * 8 + i) * 16 + kg8;
            xfrag[i] = load_cvt8(seq + ((size_t)(t + 1) * B_SZ + row) * IN_SZ + koff);
        }

        if (tid == 0) {
            while (__hip_atomic_load(ws, __ATOMIC_RELAXED,
                                     __HIP_MEMORY_SCOPE_AGENT) < t + 1)
                __builtin_amdgcn_s_sleep(1);
        }
        __syncthreads();
        __builtin_amdgcn_fence(__ATOMIC_ACQUIRE, "agent");  // inv L1/L2 -> fresh h

        // ---- load h(t) frags for next step ----
        const float* hprev = out + (size_t)t * B_SZ * H_SZ;
        #pragma unroll
        for (int i = 0; i < 8; ++i) {
            int koff = (wv * 8 + i) * 16 + kg8;
            hfrag[i] = load_cvt8(hprev + (size_t)row * H_SZ + koff);
        }
    }
}

extern "C" void kernel_launch(void* const* d_in, const int* in_sizes, int n_in,
                              void* d_out, int out_size, void* d_ws, size_t ws_size,
                              hipStream_t stream) {
    const float* seq  = (const float*)d_in[0];
    const float* h0   = (const float*)d_in[1];
    const float* c0   = (const float*)d_in[2];
    const float* W_ih = (const float*)d_in[3];
    const float* W_hh = (const float*)d_in[4];
    const float* b_ih = (const float*)d_in[5];
    const float* b_hh = (const float*)d_in[6];
    float* out = (float*)d_out;
    int* ws = (int*)d_ws;

    lstm_init_kernel<<<1, NTHR, 0, stream>>>(ws);
    lstm_persistent<<<NBLK, NTHR, 0, stream>>>(seq, h0, c0, W_ih, W_hh,
                                               b_ih, b_hh, out, ws);
}

// Round 6
// 11711.012 us; speedup vs baseline: 5.2947x; 1.4938x over previous
//
#include <hip/hip_runtime.h>
#include <math.h>

// LSTM T=2048, B=32, IN=512, H=512. Persistent kernel, 64 blocks x 256 thr.
// Block owns 8 h-cols -> 32 gate cols. Weights bf16 in LDS (B-frag order).
// Per step: MFMA 32x32 tile, K=1024 split over 4 waves, Gp LDS reduce
// (double-buffered, stride-40 padded). h(t) exchanged as bf16 via d_ws
// (double-buffered) with per-wave flags: producer wave stores h-chunk,
// s_waitcnt vmcnt(0), stores flag; consumer wave polls exactly the 64
// producer-wave flags it needs (one per lane), acquire-fence, loads frags.
// No aggregator, no go-flag, no release-fence wbl2 on the critical path.

#define T_STEPS 2048
#define B_SZ    32
#define IN_SZ   512
#define H_SZ    512
#define NBLK    64
#define NTHR    256
#define HPB     8

typedef __attribute__((ext_vector_type(8)))  short short8;
typedef __attribute__((ext_vector_type(16))) float f32x16;

__device__ __forceinline__ unsigned short f2bf(float f) {
    unsigned int u = __builtin_bit_cast(unsigned int, f);
    u += 0x7fffu + ((u >> 16) & 1u);        // round-to-nearest-even
    return (unsigned short)(u >> 16);
}
__device__ __forceinline__ float sigmoidf_(float x) { return 1.f / (1.f + __expf(-x)); }
__device__ __forceinline__ float tanhf_(float x) {
    float e = __expf(-2.f * fabsf(x));
    float t = (1.f - e) / (1.f + e);
    return copysignf(t, x);
}
__device__ __forceinline__ short8 pack8(float4 a, float4 b) {
    short8 r;
    r[0] = (short)f2bf(a.x); r[1] = (short)f2bf(a.y);
    r[2] = (short)f2bf(a.z); r[3] = (short)f2bf(a.w);
    r[4] = (short)f2bf(b.x); r[5] = (short)f2bf(b.y);
    r[6] = (short)f2bf(b.z); r[7] = (short)f2bf(b.w);
    return r;
}
__device__ __forceinline__ short8 load_cvt8(const float* p) {
    float4 a = *reinterpret_cast<const float4*>(p);
    float4 b = *reinterpret_cast<const float4*>(p + 4);
    return pack8(a, b);
}

__global__ void __launch_bounds__(NTHR) lstm_init_kernel(int* ws) {
    for (int i = threadIdx.x; i < 1024; i += NTHR) ws[i] = 0;
}

__global__ void __launch_bounds__(NTHR, 1) lstm_persistent(
    const float* __restrict__ seq,   // [T,B,IN]
    const float* __restrict__ h0,    // [B,H]
    const float* __restrict__ c0,    // [B,H]
    const float* __restrict__ W_ih,  // [4H, IN]
    const float* __restrict__ W_hh,  // [4H, H]
    const float* __restrict__ b_ih,  // [4H]
    const float* __restrict__ b_hh,  // [4H]
    float* __restrict__ out,         // [T,B,H] ++ h_f[B,H] ++ c_f[B,H]
    int* ws)
{
    __shared__ short Bl[4096 * 8];       // 64 KB, B-frag order
    __shared__ float Gp[2][4][1280];     // 40 KB, [buf][wave][row*40+col]
    __shared__ float biasl[32];

    int* flags = ws;                                          // 256 flags, stride 4 ints
    unsigned short* hx = (unsigned short*)(ws + 1024);        // ws_h[2][32][512] bf16

    const int tid = (int)threadIdx.x;
    const int blk = (int)blockIdx.x;
    const int l   = tid & 63;
    const int wv  = tid >> 6;
    const int row = l & 31;          // A row (batch) this lane supplies
    const int kg8 = (l >> 5) * 8;    // k-subchunk within 16-wide K tile
    const int m   = tid >> 3;        // epilogue batch row
    const int hi  = tid & 7;         // epilogue local h col
    const int colh = blk * HPB + hi;

    // ---- pack weights into B-fragment order (once) ----
    for (int ch = tid; ch < 4096; ch += NTHR) {
        int ktg = ch >> 6, sub = ch & 63, kg = sub >> 5, col = sub & 31;
        int j  = (col >> 3) * H_SZ + blk * HPB + (col & 7);
        int kb = ktg * 16 + kg * 8;
        const float* src = (kb < IN_SZ) ? (W_ih + (size_t)j * IN_SZ + kb)
                                        : (W_hh + (size_t)j * H_SZ + (kb - IN_SZ));
        *reinterpret_cast<short8*>(&Bl[ch * 8]) = load_cvt8(src);
    }
    if (tid < 32) {
        int j = (tid >> 3) * H_SZ + blk * HPB + (tid & 7);
        biasl[tid] = b_ih[j] + b_hh[j];
    }

    float cstate = c0[(size_t)m * H_SZ + colh];

    // ---- prologue frags (t=0): x(0) from seq, h(-1) from h0 ----
    short8 xfrag[8], hfrag[8];
    #pragma unroll
    for (int i = 0; i < 8; ++i) {
        int koff = (wv * 8 + i) * 16 + kg8;
        xfrag[i] = load_cvt8(seq + (size_t)row * IN_SZ + koff);
        hfrag[i] = load_cvt8(h0 + (size_t)row * H_SZ + koff);
    }
    __syncthreads();   // B pack + bias visible

    const short8* Bv = reinterpret_cast<const short8*>(Bl);
    // lane l of consumer wave wv polls producer block 16wv+(l>>2), wave l&3
    const int fidx = ((16 * wv + (l >> 2)) * 4 + (l & 3)) * 4;

    for (int t = 0; t < T_STEPS; ++t) {
        // ---- A. raw prefetch x(t+1) (f32, plain; cvt later off-path) ----
        int tn = (t + 1 < T_STEPS) ? t + 1 : t;
        float4 xa[8], xb[8];
        #pragma unroll
        for (int i = 0; i < 8; ++i) {
            const float* p = seq + ((size_t)tn * B_SZ + row) * IN_SZ
                           + (wv * 8 + i) * 16 + kg8;
            xa[i] = *reinterpret_cast<const float4*>(p);
            xb[i] = *reinterpret_cast<const float4*>(p + 4);
        }

        // ---- B. MFMA: partial C[32x32] over this wave's K quarter ----
        f32x16 acc = {0.f,0.f,0.f,0.f,0.f,0.f,0.f,0.f,
                      0.f,0.f,0.f,0.f,0.f,0.f,0.f,0.f};
        #pragma unroll
        for (int i = 0; i < 8; ++i)
            acc = __builtin_amdgcn_mfma_f32_32x32x16_bf16(
                xfrag[i], Bv[(wv * 8 + i) * 64 + l], acc, 0, 0, 0);
        #pragma unroll
        for (int i = 0; i < 8; ++i)
            acc = __builtin_amdgcn_mfma_f32_32x32x16_bf16(
                hfrag[i], Bv[(32 + wv * 8 + i) * 64 + l], acc, 0, 0, 0);

        // ---- C. Gp write (stride-40: write conflict-free, read 2-way) ----
        {
            float* gp = &Gp[t & 1][wv][0];
            int rb = 4 * (l >> 5), c32 = l & 31;
            #pragma unroll
            for (int r = 0; r < 16; ++r)
                gp[((r & 3) + 8 * (r >> 2) + rb) * 40 + c32] = acc[r];
        }
        __syncthreads();

        // ---- D. epilogue: reduce 4 partials, gates, state update ----
        float pg[4];
        #pragma unroll
        for (int g = 0; g < 4; ++g) {
            float s = biasl[g * 8 + hi];
            #pragma unroll
            for (int w = 0; w < 4; ++w)
                s += Gp[t & 1][w][m * 40 + g * 8 + hi];
            pg[g] = s;
        }
        float iv = sigmoidf_(pg[0]);
        float fv = sigmoidf_(pg[1]);
        float gv = tanhf_(pg[2]);
        float ov = sigmoidf_(pg[3]);
        cstate = fv * cstate + iv * gv;
        float hn = ov * tanhf_(cstate);
        out[((size_t)t * B_SZ + m) * H_SZ + colh] = hn;   // plain: only read at kernel end

        if (t == T_STEPS - 1) {
            size_t base = (size_t)T_STEPS * B_SZ * H_SZ;
            out[base + (size_t)m * H_SZ + colh] = hn;
            out[base + (size_t)B_SZ * H_SZ + (size_t)m * H_SZ + colh] = cstate;
            break;
        }

        // h(t) as bf16 -> write-through to L3 (agent scope)
        __hip_atomic_store(&hx[(size_t)(t & 1) * 16384 + (size_t)m * H_SZ + colh],
                           f2bf(hn), __ATOMIC_RELAXED, __HIP_MEMORY_SCOPE_AGENT);
        // order: h-store committed before flag (per-wave, no wbl2)
        asm volatile("s_waitcnt vmcnt(0)" ::: "memory");
        if ((tid & 63) == 0)
            __hip_atomic_store(&flags[(blk * 4 + wv) * 4], t + 1,
                               __ATOMIC_RELAXED, __HIP_MEMORY_SCOPE_AGENT);

        // ---- E. cvt x(t+1) (loads from A have had the whole step to land) ----
        #pragma unroll
        for (int i = 0; i < 8; ++i) xfrag[i] = pack8(xa[i], xb[i]);

        // ---- F. poll the 64 producer-wave flags this wave needs ----
        int v;
        do {
            v = __hip_atomic_load(&flags[fidx], __ATOMIC_RELAXED,
                                  __HIP_MEMORY_SCOPE_AGENT);
        } while (!__all(v >= t + 1));
        __builtin_amdgcn_fence(__ATOMIC_ACQUIRE, "agent");  // inv L1/L2: ws_h reused

        // ---- G. load h(t) frags directly as bf16 ----
        const unsigned short* hs = hx + (size_t)(t & 1) * 16384 + (size_t)row * H_SZ;
        #pragma unroll
        for (int i = 0; i < 8; ++i)
            hfrag[i] = *reinterpret_cast<const short8*>(hs + (wv * 8 + i) * 16 + kg8);
    }
}

extern "C" void kernel_launch(void* const* d_in, const int* in_sizes, int n_in,
                              void* d_out, int out_size, void* d_ws, size_t ws_size,
                              hipStream_t stream) {
    const float* seq  = (const float*)d_in[0];
    const float* h0   = (const float*)d_in[1];
    const float* c0   = (const float*)d_in[2];
    const float* W_ih = (const float*)d_in[3];
    const float* W_hh = (const float*)d_in[4];
    const float* b_ih = (const float*)d_in[5];
    const float* b_hh = (const float*)d_in[6];
    float* out = (float*)d_out;
    int* ws = (int*)d_ws;

    lstm_init_kernel<<<1, NTHR, 0, stream>>>(ws);
    lstm_persistent<<<NBLK, NTHR, 0, stream>>>(seq, h0, c0, W_ih, W_hh,
                                               b_ih, b_hh, out, ws);
}